// Round 3
// baseline (222.819 us; speedup 1.0000x reference)
//
#include <hip/hip_runtime.h>
#include <hip/hip_bf16.h>

// ---------------------------------------------------------------------------
// Problem constants
// ---------------------------------------------------------------------------
#define B_  2
#define N_  2048
#define D_  1024
#define H_  16
#define DH_ 64
#define BN_ROWS (B_ * N_)   // 4096
#define EPS_ 1e-5f
#define QKV_N 3072          // fused [Q | K | V] output width

typedef __attribute__((ext_vector_type(8))) short bf16x8_t;
typedef __attribute__((ext_vector_type(4))) float f32x4_t;

typedef const unsigned int __attribute__((address_space(1)))* gas_ptr;
typedef unsigned int __attribute__((address_space(3)))* las_ptr;

// async global->LDS, 16B per lane, dest = wave-uniform base + lane*16
__device__ __forceinline__ void async16(const unsigned short* g, unsigned short* l) {
    __builtin_amdgcn_global_load_lds((gas_ptr)g, (las_ptr)l, 16, 0, 0);
}

__device__ __forceinline__ unsigned short f2bf(float f) {
    unsigned int u = __float_as_uint(f);
    unsigned int r = u + 0x7FFFu + ((u >> 16) & 1u);   // round-to-nearest-even
    return (unsigned short)(r >> 16);
}

// pack two f32 -> bf16x2 (hardware v_cvt_pk_bf16_f32 where available)
__device__ __forceinline__ unsigned int pk2bf(float a, float b) {
    __hip_bfloat162 t = __float22bfloat162_rn(float2{a, b});
    return *(unsigned int*)&t;
}

// ---------------------------------------------------------------------------
// Kernel 1: fused dual LayerNorm. One block per row.
// ---------------------------------------------------------------------------
__global__ __launch_bounds__(256) void ln_dual_kernel(
    const float* __restrict__ x,
    const float* __restrict__ g1, const float* __restrict__ b1,
    const float* __restrict__ g2, const float* __restrict__ b2,
    unsigned short* __restrict__ xn, unsigned short* __restrict__ cn) {
    const int row = blockIdx.x;
    const int tid = threadIdx.x;
    const float4 v = ((const float4*)(x + (size_t)row * D_))[tid];

    float s  = v.x + v.y + v.z + v.w;
    float s2 = v.x * v.x + v.y * v.y + v.z * v.z + v.w * v.w;
    #pragma unroll
    for (int off = 32; off > 0; off >>= 1) {
        s  += __shfl_down(s,  off);
        s2 += __shfl_down(s2, off);
    }
    __shared__ float red[8];
    if ((tid & 63) == 0) { red[tid >> 6] = s; red[4 + (tid >> 6)] = s2; }
    __syncthreads();
    const float S  = red[0] + red[1] + red[2] + red[3];
    const float S2 = red[4] + red[5] + red[6] + red[7];
    const float mean = S * (1.0f / D_);
    const float var  = S2 * (1.0f / D_) - mean * mean;
    const float rstd = rsqrtf(var + EPS_);

    const float4 G1 = ((const float4*)g1)[tid];
    const float4 B1 = ((const float4*)b1)[tid];
    const float4 G2 = ((const float4*)g2)[tid];
    const float4 B2 = ((const float4*)b2)[tid];

    float nx[4] = { (v.x - mean) * rstd, (v.y - mean) * rstd,
                    (v.z - mean) * rstd, (v.w - mean) * rstd };
    ushort4 o1, o2;
    o1.x = f2bf(nx[0] * G1.x + B1.x); o1.y = f2bf(nx[1] * G1.y + B1.y);
    o1.z = f2bf(nx[2] * G1.z + B1.z); o1.w = f2bf(nx[3] * G1.w + B1.w);
    o2.x = f2bf(nx[0] * G2.x + B2.x); o2.y = f2bf(nx[1] * G2.y + B2.y);
    o2.z = f2bf(nx[2] * G2.z + B2.z); o2.w = f2bf(nx[3] * G2.w + B2.w);
    ((ushort4*)(xn + (size_t)row * D_))[tid] = o1;
    ((ushort4*)(cn + (size_t)row * D_))[tid] = o2;
}

// ---------------------------------------------------------------------------
// Kernel 2: all three weights fp32 [K=1024][N] -> bf16 transposed [N][K],
// one dispatch. z=0: Wq (N=1024), z=1: Wkv (N=2048), z=2: Wo (N=1024).
// ---------------------------------------------------------------------------
__global__ __launch_bounds__(256) void wt_transpose_all_kernel(
    const float* __restrict__ Wq, const float* __restrict__ Wkv,
    const float* __restrict__ Wo,
    unsigned short* __restrict__ wqkvT, unsigned short* __restrict__ woT) {
    const int z = blockIdx.z;
    const float* src;
    unsigned short* dst;
    int N;
    if (z == 0)      { src = Wq;  dst = wqkvT;                        N = 1024; }
    else if (z == 1) { src = Wkv; dst = wqkvT + (size_t)1024 * 1024;  N = 2048; }
    else             { src = Wo;  dst = woT;                          N = 1024; }
    const int n0 = blockIdx.x * 32, k0 = blockIdx.y * 32;
    if (n0 >= N) return;

    __shared__ float tile[32][33];
    const int tx = threadIdx.x, ty = threadIdx.y;   // 32 x 8
    #pragma unroll
    for (int i = 0; i < 4; i++)
        tile[ty + i * 8][tx] = src[(size_t)(k0 + ty + i * 8) * N + n0 + tx];
    __syncthreads();
    #pragma unroll
    for (int i = 0; i < 4; i++)
        dst[(size_t)(n0 + ty + i * 8) * 1024 + k0 + tx] = f2bf(tile[tx][ty + i * 8]);
}

// ---------------------------------------------------------------------------
// Kernel 2b: bf16 V-transpose: qkv cols [2048..3071] -> vt[b][c][n]
// ---------------------------------------------------------------------------
__global__ __launch_bounds__(256) void vt_transpose_kernel(
    const unsigned short* __restrict__ qkv, unsigned short* __restrict__ vt) {
    __shared__ unsigned short tile[32][33];
    const int b = blockIdx.z;
    const int n0 = blockIdx.x * 32, c0 = blockIdx.y * 32;
    const int tx = threadIdx.x, ty = threadIdx.y;   // 32 x 8
    #pragma unroll
    for (int i = 0; i < 4; i++)
        tile[ty + i * 8][tx] =
            qkv[(size_t)(b * N_ + n0 + ty + i * 8) * QKV_N + 2048 + c0 + tx];
    __syncthreads();
    #pragma unroll
    for (int i = 0; i < 4; i++)
        vt[(size_t)(b * 1024 + c0 + ty + i * 8) * N_ + n0 + tx] = tile[tx][ty + i * 8];
}

// ---------------------------------------------------------------------------
// Kernel 3: bf16 GEMM (m97 structure): async global->LDS staging (16B),
// XOR swizzle applied on the GLOBAL source address -> conflict-free
// ds_read_b128 fragment reads. 128x128 tile, BK=64, 4 waves x 64x64.
// FUSED: A = A0 for output cols < 1024 (Q), A1 otherwise (KV); Q outputs
// pre-scaled by 0.125*log2(e) so flash can use exp2 directly.
// ---------------------------------------------------------------------------
template <bool FUSED, bool BF16OUT>
__global__ __launch_bounds__(256, 3) void gemm_kernel(
    const unsigned short* __restrict__ A0, const unsigned short* __restrict__ A1,
    const unsigned short* __restrict__ Bt, void* __restrict__ Cv,
    int M, int N, int K) {
    __shared__ unsigned short As[128 * 64];
    __shared__ unsigned short Bs[128 * 64];
    const int tid = threadIdx.x, lane = tid & 63, w = tid >> 6;
    const int quad = lane >> 4, l16 = lane & 15;
    const int lr8 = lane >> 3, pg8 = lane & 7;
    const int wr = (w >> 1) * 64, wc = (w & 1) * 64;
    const int bm = blockIdx.y * 128, bn = blockIdx.x * 128;
    const unsigned short* A = (FUSED && bn >= 1024) ? A1 : A0;
    const float cscale = (FUSED && bn < 1024) ? 0.180336880111120f : 1.0f;

    f32x4_t acc[4][4] = {};
    for (int k0 = 0; k0 < K; k0 += 64) {
        #pragma unroll
        for (int i = 0; i < 4; i++) {
            const int rb = w * 32 + i * 8;          // 8 rows per instr
            const int r  = rb + lr8;
            const int g  = pg8 ^ (r & 7);           // swizzle via source addr
            async16(&A [(size_t)(bm + r) * K + k0 + g * 8], &As[rb * 64]);
            async16(&Bt[(size_t)(bn + r) * K + k0 + g * 8], &Bs[rb * 64]);
        }
        __syncthreads();                            // drains vmcnt + barrier
        #pragma unroll
        for (int kk = 0; kk < 64; kk += 32) {
            bf16x8_t af[4], bfr[4];
            const int g0 = (kk >> 3) + quad;
            #pragma unroll
            for (int t = 0; t < 4; t++)
                af[t] = *(const bf16x8_t*)&As[(wr + t * 16 + l16) * 64 +
                                              ((g0 ^ (l16 & 7)) * 8)];
            #pragma unroll
            for (int t = 0; t < 4; t++)
                bfr[t] = *(const bf16x8_t*)&Bs[(wc + t * 16 + l16) * 64 +
                                               ((g0 ^ (l16 & 7)) * 8)];
            #pragma unroll
            for (int mt = 0; mt < 4; mt++)
                #pragma unroll
                for (int nt = 0; nt < 4; nt++)
                    acc[mt][nt] = __builtin_amdgcn_mfma_f32_16x16x32_bf16(
                        af[mt], bfr[nt], acc[mt][nt], 0, 0, 0);
        }
        __syncthreads();
    }
    #pragma unroll
    for (int mt = 0; mt < 4; mt++)
        #pragma unroll
        for (int nt = 0; nt < 4; nt++)
            #pragma unroll
            for (int r = 0; r < 4; r++) {
                const int row = bm + wr + mt * 16 + quad * 4 + r;
                const int col = bn + wc + nt * 16 + l16;
                if (BF16OUT)
                    ((unsigned short*)Cv)[(size_t)row * N + col] =
                        f2bf(acc[mt][nt][r] * cscale);
                else
                    ((float*)Cv)[(size_t)row * N + col] = acc[mt][nt][r];
            }
}

// ---------------------------------------------------------------------------
// Kernel 4: causal flash attention, S^T scheme.
// Block = 128 queries (4 waves x 32q), pairs (qt, 15-qt) -> 256 blocks x
// uniform 34 iters = 1 block/CU. Per iter: S^T = K.Q^T (C-layout rows=keys,
// 4 contiguous query... rows per lane-reg), exp2 (Q pre-scaled), packed b64
// P-store, PV via A=P-frag, rowsums via ones-B-fragment MFMA (no shuffles).
// ---------------------------------------------------------------------------
__global__ __launch_bounds__(256, 1) void flash_attn_kernel(
    const unsigned short* __restrict__ qkv, const unsigned short* __restrict__ vt,
    unsigned short* __restrict__ out) {
    __shared__ unsigned short Qs[128 * 64];     // [query][dh], swizzled
    __shared__ unsigned short Ks[64 * 64];      // [key][dh], swizzled
    __shared__ unsigned short Vts[64 * 64];     // [dh][key], swizzled
    __shared__ unsigned short Ps[4][32 * 72];   // wave-private [query][key]

    const int tid = threadIdx.x, lane = tid & 63, w = tid >> 6;
    const int quad = lane >> 4, l16 = lane & 15;
    const int lr8 = lane >> 3, pg8 = lane & 7;
    const int pair = blockIdx.x & 7;            // 8 pairs of 128-query tiles
    const int bh = blockIdx.x >> 3;             // 0..31
    const int b = bh >> 4, h = bh & 15;

    const unsigned short* qb  = qkv + (size_t)(b * N_) * QKV_N + h * DH_;
    const unsigned short* kb  = qb + 1024;
    const unsigned short* vtb = vt + (size_t)(b * 1024 + h * DH_) * N_;

    bf16x8_t ones;
    #pragma unroll
    for (int j = 0; j < 8; j++) ones[j] = (short)0x3F80;   // bf16 1.0

    for (int phase = 0; phase < 2; phase++) {
        const int qt = phase ? (15 - pair) : pair;   // 128-query tile
        const int qs = qt * 128;
        const int niter = 2 * qt + 2;                // 64-key tiles to visit

        // stage Q tile: 128 rows, 4 instrs/wave (drained at first barrier)
        #pragma unroll
        for (int i = 0; i < 4; i++) {
            const int rb = w * 32 + i * 8;
            const int r  = rb + lr8;
            const int g  = pg8 ^ (r & 7);
            async16(&qb[(size_t)(qs + r) * QKV_N + g * 8], &Qs[rb * 64]);
        }

        f32x4_t o[2][4] = {};
        f32x4_t lacc[2] = {};
        bf16x8_t qf[2][2];      // hoisted Q B-fragments [nq][kk2]

        for (int jt = 0; jt < niter; jt++) {
            const int js = jt * 64;
            #pragma unroll
            for (int i = 0; i < 2; i++) {
                const int rb = w * 16 + i * 8;
                const int r  = rb + lr8;
                const int g  = pg8 ^ (r & 7);
                async16(&kb [(size_t)(js + r) * QKV_N + g * 8], &Ks [rb * 64]);
                async16(&vtb[(size_t)r * N_ + js + g * 8],      &Vts[rb * 64]);
            }
            __syncthreads();

            if (jt == 0) {
                #pragma unroll
                for (int nq = 0; nq < 2; nq++)
                    #pragma unroll
                    for (int k2 = 0; k2 < 2; k2++) {
                        const int g0 = k2 * 4 + quad;
                        qf[nq][k2] = *(const bf16x8_t*)&Qs[
                            (w * 32 + nq * 16 + l16) * 64 + (g0 ^ (l16 & 7)) * 8];
                    }
            }

            // S^T = K . Q^T : m = keys (4 kt tiles), n = queries (2 nq tiles)
            f32x4_t s[4][2] = {};
            #pragma unroll
            for (int k2 = 0; k2 < 2; k2++) {
                const int g0 = k2 * 4 + quad;
                #pragma unroll
                for (int kt = 0; kt < 4; kt++) {
                    const bf16x8_t a = *(const bf16x8_t*)&Ks[
                        (kt * 16 + l16) * 64 + (g0 ^ (l16 & 7)) * 8];
                    #pragma unroll
                    for (int nq = 0; nq < 2; nq++)
                        s[kt][nq] = __builtin_amdgcn_mfma_f32_16x16x32_bf16(
                            a, qf[nq][k2], s[kt][nq], 0, 0, 0);
                }
            }

            // p = exp2(s) (Q pre-scaled by 0.125*log2e); mask only last 2 iters
            const bool edge = (jt >= niter - 2);
            #pragma unroll
            for (int kt = 0; kt < 4; kt++)
                #pragma unroll
                for (int nq = 0; nq < 2; nq++) {
                    float p[4];
                    #pragma unroll
                    for (int r = 0; r < 4; r++) {
                        float sv = s[kt][nq][r];
                        if (edge) {
                            const int key = js + kt * 16 + quad * 4 + r;
                            const int qy  = qs + w * 32 + nq * 16 + l16;
                            if (key > qy) sv = -3e38f;
                        }
                        p[r] = exp2f(sv);
                    }
                    // rows contiguous: Ps[w][query][kt*16 + quad*4 .. +3]
                    uint2 pk = { pk2bf(p[0], p[1]), pk2bf(p[2], p[3]) };
                    *(uint2*)&Ps[w][(nq * 16 + l16) * 72 + kt * 16 + quad * 4] = pk;
                }

            // O += P.V ; l += P.1 (ones-fragment rowsum, accumulated)
            #pragma unroll
            for (int k2 = 0; k2 < 2; k2++) {
                const int g0 = k2 * 4 + quad;
                bf16x8_t ap[2];
                #pragma unroll
                for (int mq = 0; mq < 2; mq++)
                    ap[mq] = *(const bf16x8_t*)&Ps[w][
                        (mq * 16 + l16) * 72 + k2 * 32 + quad * 8];
                #pragma unroll
                for (int nt = 0; nt < 4; nt++) {
                    const bf16x8_t bv = *(const bf16x8_t*)&Vts[
                        (nt * 16 + l16) * 64 + (g0 ^ (l16 & 7)) * 8];
                    #pragma unroll
                    for (int mq = 0; mq < 2; mq++)
                        o[mq][nt] = __builtin_amdgcn_mfma_f32_16x16x32_bf16(
                            ap[mq], bv, o[mq][nt], 0, 0, 0);
                }
                #pragma unroll
                for (int mq = 0; mq < 2; mq++)
                    lacc[mq] = __builtin_amdgcn_mfma_f32_16x16x32_bf16(
                        ap[mq], ones, lacc[mq], 0, 0, 0);
            }
            __syncthreads();   // before next iter overwrites Ks/Vts (or Qs)
        }

        // epilogue: normalize with MFMA-accumulated rowsums (no shuffles)
        #pragma unroll
        for (int mq = 0; mq < 2; mq++)
            #pragma unroll
            for (int r = 0; r < 4; r++) {
                const float inv = 1.0f / lacc[mq][r];
                const int row = b * N_ + qs + w * 32 + mq * 16 + quad * 4 + r;
                #pragma unroll
                for (int nt = 0; nt < 4; nt++) {
                    const int col = h * DH_ + nt * 16 + l16;
                    out[(size_t)row * (H_ * DH_) + col] = f2bf(o[mq][nt][r] * inv);
                }
            }
    }
}

// ---------------------------------------------------------------------------
// Host launcher
// ---------------------------------------------------------------------------
extern "C" void kernel_launch(void* const* d_in, const int* in_sizes, int n_in,
                              void* d_out, int out_size, void* d_ws, size_t ws_size,
                              hipStream_t stream) {
    const float* x     = (const float*)d_in[0];
    const float* ln_g  = (const float*)d_in[1];
    const float* ln_b  = (const float*)d_in[2];
    const float* lnc_g = (const float*)d_in[3];
    const float* lnc_b = (const float*)d_in[4];
    const float* Wq    = (const float*)d_in[5];
    const float* Wkv   = (const float*)d_in[6];
    const float* Wo    = (const float*)d_in[7];

    char* ws = (char*)d_ws;
    const size_t MB = 1024 * 1024;
    unsigned short* qkv   = (unsigned short*)(ws + 0 * MB);    // [4096][3072] 24 MB
    unsigned short* vtbuf = (unsigned short*)(ws + 24 * MB);   // [2048][2048]  8 MB
    unsigned short* xn    = (unsigned short*)(ws + 32 * MB);   // [4096][1024]  8 MB
    unsigned short* cn    = (unsigned short*)(ws + 40 * MB);   // [4096][1024]  8 MB
    unsigned short* wqkvT = (unsigned short*)(ws + 48 * MB);   // [3072][1024]  6 MB
    unsigned short* woT   = (unsigned short*)(ws + 54 * MB);   // [1024][1024]  2 MB
    unsigned short* ao    = xn;   // reuse: xn dead after QKV GEMM

    ln_dual_kernel<<<BN_ROWS, 256, 0, stream>>>(x, ln_g, ln_b, lnc_g, lnc_b, xn, cn);

    wt_transpose_all_kernel<<<dim3(64, 32, 3), dim3(32, 8), 0, stream>>>(
        Wq, Wkv, Wo, wqkvT, woT);

    // fused Q+KV GEMM: [4096][3072] = {xn|cn} @ wqkvT^T ; Q pre-scaled
    gemm_kernel<true, true><<<dim3(QKV_N / 128, BN_ROWS / 128), 256, 0, stream>>>(
        xn, cn, wqkvT, qkv, BN_ROWS, QKV_N, D_);

    // V columns -> vt[b][h*64+dh][n]
    vt_transpose_kernel<<<dim3(64, 32, 2), dim3(32, 8), 0, stream>>>(qkv, vtbuf);

    flash_attn_kernel<<<B_ * H_ * 8, 256, 0, stream>>>(qkv, vtbuf, ao);

    // out = ao @ woT^T (fp32 out)
    gemm_kernel<false, false><<<dim3(D_ / 128, BN_ROWS / 128), 256, 0, stream>>>(
        ao, nullptr, woT, (float*)d_out, BN_ROWS, D_, H_ * DH_);
}

// Round 4
// 198.944 us; speedup vs baseline: 1.1200x; 1.1200x over previous
//
#include <hip/hip_runtime.h>
#include <hip/hip_bf16.h>

// ---------------------------------------------------------------------------
// Problem constants
// ---------------------------------------------------------------------------
#define B_  2
#define N_  2048
#define D_  1024
#define H_  16
#define DH_ 64
#define BN_ROWS (B_ * N_)   // 4096
#define EPS_ 1e-5f
#define QKV_N 3072          // fused [Q | K | V] output width

typedef __attribute__((ext_vector_type(8))) short bf16x8_t;
typedef __attribute__((ext_vector_type(4))) float f32x4_t;

typedef const unsigned int __attribute__((address_space(1)))* gas_ptr;
typedef unsigned int __attribute__((address_space(3)))* las_ptr;

// async global->LDS, 16B per lane, dest = wave-uniform base + lane*16
__device__ __forceinline__ void async16(const unsigned short* g, unsigned short* l) {
    __builtin_amdgcn_global_load_lds((gas_ptr)g, (las_ptr)l, 16, 0, 0);
}

__device__ __forceinline__ unsigned short f2bf(float f) {
    unsigned int u = __float_as_uint(f);
    unsigned int r = u + 0x7FFFu + ((u >> 16) & 1u);   // round-to-nearest-even
    return (unsigned short)(r >> 16);
}

// pack two f32 -> bf16x2
__device__ __forceinline__ unsigned int pk2bf(float a, float b) {
    __hip_bfloat162 t = __float22bfloat162_rn(float2{a, b});
    return *(unsigned int*)&t;
}

// ---------------------------------------------------------------------------
// Kernel 1: fused dual LayerNorm. One block per row.
// ---------------------------------------------------------------------------
__global__ __launch_bounds__(256) void ln_dual_kernel(
    const float* __restrict__ x,
    const float* __restrict__ g1, const float* __restrict__ b1,
    const float* __restrict__ g2, const float* __restrict__ b2,
    unsigned short* __restrict__ xn, unsigned short* __restrict__ cn) {
    const int row = blockIdx.x;
    const int tid = threadIdx.x;
    const float4 v = ((const float4*)(x + (size_t)row * D_))[tid];

    float s  = v.x + v.y + v.z + v.w;
    float s2 = v.x * v.x + v.y * v.y + v.z * v.z + v.w * v.w;
    #pragma unroll
    for (int off = 32; off > 0; off >>= 1) {
        s  += __shfl_down(s,  off);
        s2 += __shfl_down(s2, off);
    }
    __shared__ float red[8];
    if ((tid & 63) == 0) { red[tid >> 6] = s; red[4 + (tid >> 6)] = s2; }
    __syncthreads();
    const float S  = red[0] + red[1] + red[2] + red[3];
    const float S2 = red[4] + red[5] + red[6] + red[7];
    const float mean = S * (1.0f / D_);
    const float var  = S2 * (1.0f / D_) - mean * mean;
    const float rstd = rsqrtf(var + EPS_);

    const float4 G1 = ((const float4*)g1)[tid];
    const float4 B1 = ((const float4*)b1)[tid];
    const float4 G2 = ((const float4*)g2)[tid];
    const float4 B2 = ((const float4*)b2)[tid];

    float nx[4] = { (v.x - mean) * rstd, (v.y - mean) * rstd,
                    (v.z - mean) * rstd, (v.w - mean) * rstd };
    ushort4 o1, o2;
    o1.x = f2bf(nx[0] * G1.x + B1.x); o1.y = f2bf(nx[1] * G1.y + B1.y);
    o1.z = f2bf(nx[2] * G1.z + B1.z); o1.w = f2bf(nx[3] * G1.w + B1.w);
    o2.x = f2bf(nx[0] * G2.x + B2.x); o2.y = f2bf(nx[1] * G2.y + B2.y);
    o2.z = f2bf(nx[2] * G2.z + B2.z); o2.w = f2bf(nx[3] * G2.w + B2.w);
    ((ushort4*)(xn + (size_t)row * D_))[tid] = o1;
    ((ushort4*)(cn + (size_t)row * D_))[tid] = o2;
}

// ---------------------------------------------------------------------------
// Kernel 2: all three weights fp32 [K=1024][N] -> bf16 transposed [N][K].
// ---------------------------------------------------------------------------
__global__ __launch_bounds__(256) void wt_transpose_all_kernel(
    const float* __restrict__ Wq, const float* __restrict__ Wkv,
    const float* __restrict__ Wo,
    unsigned short* __restrict__ wqkvT, unsigned short* __restrict__ woT) {
    const int z = blockIdx.z;
    const float* src;
    unsigned short* dst;
    int N;
    if (z == 0)      { src = Wq;  dst = wqkvT;                        N = 1024; }
    else if (z == 1) { src = Wkv; dst = wqkvT + (size_t)1024 * 1024;  N = 2048; }
    else             { src = Wo;  dst = woT;                          N = 1024; }
    const int n0 = blockIdx.x * 32, k0 = blockIdx.y * 32;
    if (n0 >= N) return;

    __shared__ float tile[32][33];
    const int tx = threadIdx.x, ty = threadIdx.y;   // 32 x 8
    #pragma unroll
    for (int i = 0; i < 4; i++)
        tile[ty + i * 8][tx] = src[(size_t)(k0 + ty + i * 8) * N + n0 + tx];
    __syncthreads();
    #pragma unroll
    for (int i = 0; i < 4; i++)
        dst[(size_t)(n0 + ty + i * 8) * 1024 + k0 + tx] = f2bf(tile[tx][ty + i * 8]);
}

// ---------------------------------------------------------------------------
// Kernel 2b: bf16 V-transpose: qkv cols [2048..3071] -> vt[b][c][n]
// ---------------------------------------------------------------------------
__global__ __launch_bounds__(256) void vt_transpose_kernel(
    const unsigned short* __restrict__ qkv, unsigned short* __restrict__ vt) {
    __shared__ unsigned short tile[32][33];
    const int b = blockIdx.z;
    const int n0 = blockIdx.x * 32, c0 = blockIdx.y * 32;
    const int tx = threadIdx.x, ty = threadIdx.y;   // 32 x 8
    #pragma unroll
    for (int i = 0; i < 4; i++)
        tile[ty + i * 8][tx] =
            qkv[(size_t)(b * N_ + n0 + ty + i * 8) * QKV_N + 2048 + c0 + tx];
    __syncthreads();
    #pragma unroll
    for (int i = 0; i < 4; i++)
        vt[(size_t)(b * 1024 + c0 + ty + i * 8) * N_ + n0 + tx] = tile[tx][ty + i * 8];
}

// ---------------------------------------------------------------------------
// Kernel 3: bf16 GEMM (m97 structure), templated on BM (128 or 64).
// async global->LDS (16B) staging, XOR swizzle on the GLOBAL source address
// -> conflict-free ds_read_b128. 4 waves in 2x2, each (BM/2)x64.
// FUSED: A = A0 for output cols < 1024 (Q, pre-scaled by 0.125*log2e), A1 else.
// ---------------------------------------------------------------------------
template <int BM, bool FUSED, bool BF16OUT, int MINW>
__global__ __launch_bounds__(256, MINW) void gemm_kernel(
    const unsigned short* __restrict__ A0, const unsigned short* __restrict__ A1,
    const unsigned short* __restrict__ Bt, void* __restrict__ Cv,
    int M, int N, int K) {
    constexpr int WM = BM / 2, MT = WM / 16, AI = BM / 32;
    __shared__ unsigned short As[BM * 64];
    __shared__ unsigned short Bs[128 * 64];
    const int tid = threadIdx.x, lane = tid & 63, w = tid >> 6;
    const int quad = lane >> 4, l16 = lane & 15;
    const int lr8 = lane >> 3, pg8 = lane & 7;
    const int wr = (w >> 1) * WM, wc = (w & 1) * 64;
    const int bm = blockIdx.y * BM, bn = blockIdx.x * 128;
    const unsigned short* A = (FUSED && bn >= 1024) ? A1 : A0;
    const float cscale = (FUSED && bn < 1024) ? 0.180336880111120f : 1.0f;

    f32x4_t acc[MT][4] = {};
    for (int k0 = 0; k0 < K; k0 += 64) {
        #pragma unroll
        for (int i = 0; i < AI; i++) {
            const int rb = w * (BM / 4) + i * 8;
            const int r  = rb + lr8;
            const int g  = pg8 ^ (r & 7);
            async16(&A[(size_t)(bm + r) * K + k0 + g * 8], &As[rb * 64]);
        }
        #pragma unroll
        for (int i = 0; i < 4; i++) {
            const int rb = w * 32 + i * 8;
            const int r  = rb + lr8;
            const int g  = pg8 ^ (r & 7);
            async16(&Bt[(size_t)(bn + r) * K + k0 + g * 8], &Bs[rb * 64]);
        }
        __syncthreads();
        #pragma unroll
        for (int kk = 0; kk < 64; kk += 32) {
            bf16x8_t af[MT], bfr[4];
            const int g0 = (kk >> 3) + quad;
            #pragma unroll
            for (int t = 0; t < MT; t++)
                af[t] = *(const bf16x8_t*)&As[(wr + t * 16 + l16) * 64 +
                                              ((g0 ^ (l16 & 7)) * 8)];
            #pragma unroll
            for (int t = 0; t < 4; t++)
                bfr[t] = *(const bf16x8_t*)&Bs[(wc + t * 16 + l16) * 64 +
                                               ((g0 ^ (l16 & 7)) * 8)];
            #pragma unroll
            for (int mt = 0; mt < MT; mt++)
                #pragma unroll
                for (int nt = 0; nt < 4; nt++)
                    acc[mt][nt] = __builtin_amdgcn_mfma_f32_16x16x32_bf16(
                        af[mt], bfr[nt], acc[mt][nt], 0, 0, 0);
        }
        __syncthreads();
    }
    #pragma unroll
    for (int mt = 0; mt < MT; mt++)
        #pragma unroll
        for (int nt = 0; nt < 4; nt++)
            #pragma unroll
            for (int r = 0; r < 4; r++) {
                const int row = bm + wr + mt * 16 + quad * 4 + r;
                const int col = bn + wc + nt * 16 + l16;
                if (BF16OUT)
                    ((unsigned short*)Cv)[(size_t)row * N + col] =
                        f2bf(acc[mt][nt][r] * cscale);
                else
                    ((float*)Cv)[(size_t)row * N + col] = acc[mt][nt][r];
            }
}

// ---------------------------------------------------------------------------
// Kernel 4: causal flash attention, S^T scheme, double-buffered K/V.
// 64-query tiles paired (qt, 31-qt): 512 blocks = 2/CU = 2 waves/SIMD.
// Per iter ONE barrier; prefetch of tile jt+1 issued right after it (full
// compute phase to land before the next barrier's vmcnt drain).
// 16 q/wave: S^T = K.Q^T (keys=m, queries=n), exp2 (Q pre-scaled), packed
// b64 P-store into wave-private LDS, PV + ones-MFMA rowsums.
// ---------------------------------------------------------------------------
__global__ __launch_bounds__(256, 2) void flash_attn_kernel(
    const unsigned short* __restrict__ qkv, const unsigned short* __restrict__ vt,
    unsigned short* __restrict__ out) {
    __shared__ unsigned short Qs[64 * 64];       // [query][dh], swizzled
    __shared__ unsigned short Ks[2][64 * 64];    // [key][dh], swizzled, dbuf
    __shared__ unsigned short Vts[2][64 * 64];   // [dh][key], swizzled, dbuf
    __shared__ unsigned short Ps[4][16 * 72];    // wave-private [query][key]

    const int tid = threadIdx.x, lane = tid & 63, w = tid >> 6;
    const int quad = lane >> 4, l16 = lane & 15;
    const int lr8 = lane >> 3, pg8 = lane & 7;
    const int pair = blockIdx.x & 15;            // 16 pairs of 64q tiles
    const int bh = blockIdx.x >> 4;              // 0..31
    const int b = bh >> 4, h = bh & 15;

    const unsigned short* qb  = qkv + (size_t)(b * N_) * QKV_N + h * DH_;
    const unsigned short* kb  = qb + 1024;
    const unsigned short* vtb = vt + (size_t)(b * 1024 + h * DH_) * N_;

    bf16x8_t ones;
    #pragma unroll
    for (int j = 0; j < 8; j++) ones[j] = (short)0x3F80;   // bf16 1.0

    for (int phase = 0; phase < 2; phase++) {
        const int qt = phase ? (31 - pair) : pair;   // 64-query tile index
        const int qs = qt * 64;
        const int niter = qt + 1;

        __syncthreads();   // previous phase fully done with Qs/Ks/Vts

        // stage Q (2 instrs/wave) + K/V tile 0 into buffer 0
        #pragma unroll
        for (int i = 0; i < 2; i++) {
            const int rb = w * 16 + i * 8;
            const int r  = rb + lr8;
            const int g  = pg8 ^ (r & 7);
            async16(&qb[(size_t)(qs + r) * QKV_N + g * 8], &Qs[rb * 64]);
            async16(&kb[(size_t)r * QKV_N + g * 8], &Ks[0][rb * 64]);
            async16(&vtb[(size_t)r * N_ + g * 8],   &Vts[0][rb * 64]);
        }

        f32x4_t o[4] = {};
        f32x4_t lacc = {};
        bf16x8_t qf[2];

        for (int jt = 0; jt < niter; jt++) {
            // ends compute jt-1 (all waves) AND drains stage for buf[jt&1]
            __syncthreads();

            // prefetch next K/V tile into the other buffer (safe: previous
            // reader of that buffer finished before the barrier above)
            if (jt + 1 < niter) {
                const int js = (jt + 1) * 64;
                const int bsel = (jt + 1) & 1;
                #pragma unroll
                for (int i = 0; i < 2; i++) {
                    const int rb = w * 16 + i * 8;
                    const int r  = rb + lr8;
                    const int g  = pg8 ^ (r & 7);
                    async16(&kb[(size_t)(js + r) * QKV_N + g * 8], &Ks[bsel][rb * 64]);
                    async16(&vtb[(size_t)r * N_ + js + g * 8],     &Vts[bsel][rb * 64]);
                }
            }
            const int buf = jt & 1;
            const int js = jt * 64;

            if (jt == 0) {
                #pragma unroll
                for (int k2 = 0; k2 < 2; k2++) {
                    const int g0 = k2 * 4 + quad;
                    qf[k2] = *(const bf16x8_t*)&Qs[
                        (w * 16 + l16) * 64 + (g0 ^ (l16 & 7)) * 8];
                }
            }

            // S^T = K . Q^T : m = 64 keys (4 kt), n = 16 queries of this wave
            f32x4_t s[4] = {};
            #pragma unroll
            for (int k2 = 0; k2 < 2; k2++) {
                const int g0 = k2 * 4 + quad;
                #pragma unroll
                for (int kt = 0; kt < 4; kt++) {
                    const bf16x8_t a = *(const bf16x8_t*)&Ks[buf][
                        (kt * 16 + l16) * 64 + (g0 ^ (l16 & 7)) * 8];
                    s[kt] = __builtin_amdgcn_mfma_f32_16x16x32_bf16(
                        a, qf[k2], s[kt], 0, 0, 0);
                }
            }

            // p = exp2(s) (Q pre-scaled); mask only on the diagonal tile
            const bool edge = (jt == niter - 1);
            #pragma unroll
            for (int kt = 0; kt < 4; kt++) {
                float p[4];
                #pragma unroll
                for (int r = 0; r < 4; r++) {
                    float sv = s[kt][r];
                    if (edge) {
                        const int key = js + kt * 16 + quad * 4 + r;
                        const int qy  = qs + w * 16 + l16;
                        if (key > qy) sv = -3e38f;
                    }
                    p[r] = exp2f(sv);
                }
                uint2 pk = { pk2bf(p[0], p[1]), pk2bf(p[2], p[3]) };
                *(uint2*)&Ps[w][l16 * 72 + kt * 16 + quad * 4] = pk;
            }
            // no barrier: Ps wave-private, lgkmcnt ordering suffices

            // O += P.V ; l += P.1
            #pragma unroll
            for (int k2 = 0; k2 < 2; k2++) {
                const int g0 = k2 * 4 + quad;
                const bf16x8_t ap = *(const bf16x8_t*)&Ps[w][
                    l16 * 72 + k2 * 32 + quad * 8];
                #pragma unroll
                for (int nt = 0; nt < 4; nt++) {
                    const bf16x8_t bv = *(const bf16x8_t*)&Vts[buf][
                        (nt * 16 + l16) * 64 + (g0 ^ (l16 & 7)) * 8];
                    o[nt] = __builtin_amdgcn_mfma_f32_16x16x32_bf16(
                        ap, bv, o[nt], 0, 0, 0);
                }
                lacc = __builtin_amdgcn_mfma_f32_16x16x32_bf16(
                    ap, ones, lacc, 0, 0, 0);
            }
        }

        // epilogue: C rows = queries (quad*4+r), cols = dh (nt*16+l16)
        #pragma unroll
        for (int r = 0; r < 4; r++) {
            const float inv = 1.0f / lacc[r];
            const int query = qs + w * 16 + quad * 4 + r;
            const int row = b * N_ + query;
            #pragma unroll
            for (int nt = 0; nt < 4; nt++) {
                const int col = h * DH_ + nt * 16 + l16;
                out[(size_t)row * (H_ * DH_) + col] = f2bf(o[nt][r] * inv);
            }
        }
    }
}

// ---------------------------------------------------------------------------
// Host launcher
// ---------------------------------------------------------------------------
extern "C" void kernel_launch(void* const* d_in, const int* in_sizes, int n_in,
                              void* d_out, int out_size, void* d_ws, size_t ws_size,
                              hipStream_t stream) {
    const float* x     = (const float*)d_in[0];
    const float* ln_g  = (const float*)d_in[1];
    const float* ln_b  = (const float*)d_in[2];
    const float* lnc_g = (const float*)d_in[3];
    const float* lnc_b = (const float*)d_in[4];
    const float* Wq    = (const float*)d_in[5];
    const float* Wkv   = (const float*)d_in[6];
    const float* Wo    = (const float*)d_in[7];

    char* ws = (char*)d_ws;
    const size_t MB = 1024 * 1024;
    unsigned short* qkv   = (unsigned short*)(ws + 0 * MB);    // [4096][3072] 24 MB
    unsigned short* vtbuf = (unsigned short*)(ws + 24 * MB);   // [2048][2048]  8 MB
    unsigned short* xn    = (unsigned short*)(ws + 32 * MB);   // [4096][1024]  8 MB
    unsigned short* cn    = (unsigned short*)(ws + 40 * MB);   // [4096][1024]  8 MB
    unsigned short* wqkvT = (unsigned short*)(ws + 48 * MB);   // [3072][1024]  6 MB
    unsigned short* woT   = (unsigned short*)(ws + 54 * MB);   // [1024][1024]  2 MB
    unsigned short* ao    = xn;   // reuse: xn dead after QKV GEMM

    ln_dual_kernel<<<BN_ROWS, 256, 0, stream>>>(x, ln_g, ln_b, lnc_g, lnc_b, xn, cn);

    wt_transpose_all_kernel<<<dim3(64, 32, 3), dim3(32, 8), 0, stream>>>(
        Wq, Wkv, Wo, wqkvT, woT);

    // fused Q+KV GEMM: [4096][3072] = {xn|cn} @ wqkvT^T ; Q pre-scaled
    gemm_kernel<128, true, true, 3>
        <<<dim3(QKV_N / 128, BN_ROWS / 128), 256, 0, stream>>>(
        xn, cn, wqkvT, qkv, BN_ROWS, QKV_N, D_);

    // V columns -> vt[b][h*64+dh][n]
    vt_transpose_kernel<<<dim3(64, 32, 2), dim3(32, 8), 0, stream>>>(qkv, vtbuf);

    flash_attn_kernel<<<B_ * H_ * 16, 256, 0, stream>>>(qkv, vtbuf, ao);

    // out = ao @ woT^T (fp32 out); BM=64 -> 512 blocks = 2/CU
    gemm_kernel<64, false, false, 2>
        <<<dim3(D_ / 128, BN_ROWS / 64), 256, 0, stream>>>(
        ao, nullptr, woT, (float*)d_out, BN_ROWS, D_, H_ * DH_);
}

// Round 5
// 179.486 us; speedup vs baseline: 1.2414x; 1.1084x over previous
//
#include <hip/hip_runtime.h>
#include <hip/hip_bf16.h>

// ---------------------------------------------------------------------------
// Problem constants
// ---------------------------------------------------------------------------
#define B_  2
#define N_  2048
#define D_  1024
#define H_  16
#define DH_ 64
#define BN_ROWS (B_ * N_)   // 4096
#define EPS_ 1e-5f
#define QKV_N 3072          // fused [Q | K | V] output width

typedef __attribute__((ext_vector_type(8))) short bf16x8_t;
typedef __attribute__((ext_vector_type(4))) float f32x4_t;

typedef const unsigned int __attribute__((address_space(1)))* gas_ptr;
typedef unsigned int __attribute__((address_space(3)))* las_ptr;

// async global->LDS, 16B per lane, dest = wave-uniform base + lane*16
__device__ __forceinline__ void async16(const unsigned short* g, unsigned short* l) {
    __builtin_amdgcn_global_load_lds((gas_ptr)g, (las_ptr)l, 16, 0, 0);
}

__device__ __forceinline__ unsigned short f2bf(float f) {
    unsigned int u = __float_as_uint(f);
    unsigned int r = u + 0x7FFFu + ((u >> 16) & 1u);   // round-to-nearest-even
    return (unsigned short)(r >> 16);
}

// pack two f32 -> bf16x2
__device__ __forceinline__ unsigned int pk2bf(float a, float b) {
    __hip_bfloat162 t = __float22bfloat162_rn(float2{a, b});
    return *(unsigned int*)&t;
}

// ---------------------------------------------------------------------------
// Kernel 1: fused dual LayerNorm + all-weight bf16 transposes (one dispatch).
// blocks [0,4096): LN rows. blocks [4096,8192): weight transpose tiles.
// ---------------------------------------------------------------------------
__global__ __launch_bounds__(256) void ln_wt_kernel(
    const float* __restrict__ x,
    const float* __restrict__ g1, const float* __restrict__ b1,
    const float* __restrict__ g2, const float* __restrict__ b2,
    const float* __restrict__ Wq, const float* __restrict__ Wkv,
    const float* __restrict__ Wo,
    unsigned short* __restrict__ xn, unsigned short* __restrict__ cn,
    unsigned short* __restrict__ wqkvT, unsigned short* __restrict__ woT) {
    const int bid = blockIdx.x;
    const int tid = threadIdx.x;

    if (bid < BN_ROWS) {
        // ---- LayerNorm path ----
        const int row = bid;
        const float4 v = ((const float4*)(x + (size_t)row * D_))[tid];

        float s  = v.x + v.y + v.z + v.w;
        float s2 = v.x * v.x + v.y * v.y + v.z * v.z + v.w * v.w;
        #pragma unroll
        for (int off = 32; off > 0; off >>= 1) {
            s  += __shfl_down(s,  off);
            s2 += __shfl_down(s2, off);
        }
        __shared__ float red[8];
        if ((tid & 63) == 0) { red[tid >> 6] = s; red[4 + (tid >> 6)] = s2; }
        __syncthreads();
        const float S  = red[0] + red[1] + red[2] + red[3];
        const float S2 = red[4] + red[5] + red[6] + red[7];
        const float mean = S * (1.0f / D_);
        const float var  = S2 * (1.0f / D_) - mean * mean;
        const float rstd = rsqrtf(var + EPS_);

        const float4 G1 = ((const float4*)g1)[tid];
        const float4 B1 = ((const float4*)b1)[tid];
        const float4 G2 = ((const float4*)g2)[tid];
        const float4 B2 = ((const float4*)b2)[tid];

        float nx[4] = { (v.x - mean) * rstd, (v.y - mean) * rstd,
                        (v.z - mean) * rstd, (v.w - mean) * rstd };
        ushort4 o1, o2;
        o1.x = f2bf(nx[0] * G1.x + B1.x); o1.y = f2bf(nx[1] * G1.y + B1.y);
        o1.z = f2bf(nx[2] * G1.z + B1.z); o1.w = f2bf(nx[3] * G1.w + B1.w);
        o2.x = f2bf(nx[0] * G2.x + B2.x); o2.y = f2bf(nx[1] * G2.y + B2.y);
        o2.z = f2bf(nx[2] * G2.z + B2.z); o2.w = f2bf(nx[3] * G2.w + B2.w);
        ((ushort4*)(xn + (size_t)row * D_))[tid] = o1;
        ((ushort4*)(cn + (size_t)row * D_))[tid] = o2;
    } else {
        // ---- weight transpose path: fp32 [K=1024][N] -> bf16 [N][1024] ----
        const int zz = bid - BN_ROWS;           // 0..4095
        const float* src;
        unsigned short* dst;
        int N, t;
        if (zz < 1024)      { src = Wq;  dst = wqkvT;                       N = 1024; t = zz; }
        else if (zz < 3072) { src = Wkv; dst = wqkvT + (size_t)1024 * 1024; N = 2048; t = zz - 1024; }
        else                { src = Wo;  dst = woT;                         N = 1024; t = zz - 3072; }
        const int nb = N / 32;
        const int n0 = (t % nb) * 32, k0 = (t / nb) * 32;

        __shared__ float tile[32][33];
        const int tx = tid & 31, ty = tid >> 5;   // 32 x 8
        #pragma unroll
        for (int i = 0; i < 4; i++)
            tile[ty + i * 8][tx] = src[(size_t)(k0 + ty + i * 8) * N + n0 + tx];
        __syncthreads();
        #pragma unroll
        for (int i = 0; i < 4; i++)
            dst[(size_t)(n0 + ty + i * 8) * 1024 + k0 + tx] = f2bf(tile[tx][ty + i * 8]);
    }
}

// ---------------------------------------------------------------------------
// Kernel 2: bf16 GEMM (m97 structure), templated on BM (128 or 64).
// async global->LDS (16B) staging, XOR swizzle on the GLOBAL source address
// -> conflict-free ds_read_b128. 4 waves in 2x2, each (BM/2)x64.
// FUSED (QKV): A = A0 (Q, pre-scaled 0.125*log2e) for cols<1024 else A1 (KV);
//   V region (cols>=2048) is written TRANSPOSED-TILED to vt:
//   vt[((b*32+kt)*1024 + c)*64 + key_in_tile]  (b64 packed stores).
// ---------------------------------------------------------------------------
template <int BM, bool FUSED, bool BF16OUT>
__global__ __launch_bounds__(256, 2) void gemm_kernel(
    const unsigned short* __restrict__ A0, const unsigned short* __restrict__ A1,
    const unsigned short* __restrict__ Bt, void* __restrict__ Cv,
    unsigned short* __restrict__ vt, int M, int N, int K) {
    constexpr int WM = BM / 2, MT = WM / 16, AI = BM / 32;
    __shared__ unsigned short As[BM * 64];
    __shared__ unsigned short Bs[128 * 64];
    const int tid = threadIdx.x, lane = tid & 63, w = tid >> 6;
    const int quad = lane >> 4, l16 = lane & 15;
    const int lr8 = lane >> 3, pg8 = lane & 7;
    const int wr = (w >> 1) * WM, wc = (w & 1) * 64;
    const int bm = blockIdx.y * BM, bn = blockIdx.x * 128;
    const unsigned short* A = (FUSED && bn >= 1024) ? A1 : A0;
    const float cscale = (FUSED && bn < 1024) ? 0.180336880111120f : 1.0f;

    f32x4_t acc[MT][4] = {};
    for (int k0 = 0; k0 < K; k0 += 64) {
        #pragma unroll
        for (int i = 0; i < AI; i++) {
            const int rb = w * (BM / 4) + i * 8;
            const int r  = rb + lr8;
            const int g  = pg8 ^ (r & 7);
            async16(&A[(size_t)(bm + r) * K + k0 + g * 8], &As[rb * 64]);
        }
        #pragma unroll
        for (int i = 0; i < 4; i++) {
            const int rb = w * 32 + i * 8;
            const int r  = rb + lr8;
            const int g  = pg8 ^ (r & 7);
            async16(&Bt[(size_t)(bn + r) * K + k0 + g * 8], &Bs[rb * 64]);
        }
        __syncthreads();
        #pragma unroll
        for (int kk = 0; kk < 64; kk += 32) {
            bf16x8_t af[MT], bfr[4];
            const int g0 = (kk >> 3) + quad;
            #pragma unroll
            for (int t = 0; t < MT; t++)
                af[t] = *(const bf16x8_t*)&As[(wr + t * 16 + l16) * 64 +
                                              ((g0 ^ (l16 & 7)) * 8)];
            #pragma unroll
            for (int t = 0; t < 4; t++)
                bfr[t] = *(const bf16x8_t*)&Bs[(wc + t * 16 + l16) * 64 +
                                               ((g0 ^ (l16 & 7)) * 8)];
            #pragma unroll
            for (int mt = 0; mt < MT; mt++)
                #pragma unroll
                for (int nt = 0; nt < 4; nt++)
                    acc[mt][nt] = __builtin_amdgcn_mfma_f32_16x16x32_bf16(
                        af[mt], bfr[nt], acc[mt][nt], 0, 0, 0);
        }
        __syncthreads();
    }

    if (FUSED && bn >= 2048) {
        // V region -> tiled transpose into vt. Wave tile = 64 seq x 64 cols.
        const int seq0 = bm + wr;                 // multiple of 64
        const int bq = seq0 >> 11;                // batch
        const int kt = (seq0 & (N_ - 1)) >> 6;    // 64-key tile within batch
        #pragma unroll
        for (int nt = 0; nt < 4; nt++) {
            const int c = (bn - 2048) + wc + nt * 16 + l16;   // 0..1023
            unsigned short* dst =
                vt + (((size_t)(bq * 32 + kt) * 1024) + c) * 64;
            #pragma unroll
            for (int mt = 0; mt < 4; mt++) {
                uint2 v2 = { pk2bf(acc[mt][nt][0], acc[mt][nt][1]),
                             pk2bf(acc[mt][nt][2], acc[mt][nt][3]) };
                *(uint2*)&dst[mt * 16 + quad * 4] = v2;   // 4 consecutive keys
            }
        }
        return;
    }

    #pragma unroll
    for (int mt = 0; mt < MT; mt++)
        #pragma unroll
        for (int nt = 0; nt < 4; nt++)
            #pragma unroll
            for (int r = 0; r < 4; r++) {
                const int row = bm + wr + mt * 16 + quad * 4 + r;
                const int col = bn + wc + nt * 16 + l16;
                if (BF16OUT)
                    ((unsigned short*)Cv)[(size_t)row * N + col] =
                        f2bf(acc[mt][nt][r] * cscale);
                else
                    ((float*)Cv)[(size_t)row * N + col] = acc[mt][nt][r];
            }
}

// ---------------------------------------------------------------------------
// Kernel 3: causal flash attention, S^T scheme, double-buffered K/V,
// XCD-aware swizzle: all 16 pair-blocks of one (b,h) -> one XCD (L2 reuse).
// 64-query tiles paired (qt, 31-qt): 512 blocks = 2/CU.
// V read from tiled-transposed vt (written by the QKV GEMM epilogue).
// ---------------------------------------------------------------------------
__global__ __launch_bounds__(256, 2) void flash_attn_kernel(
    const unsigned short* __restrict__ qkv, const unsigned short* __restrict__ vt,
    unsigned short* __restrict__ out) {
    __shared__ unsigned short Qs[64 * 64];       // [query][dh], swizzled
    __shared__ unsigned short Ks[2][64 * 64];    // [key][dh], swizzled, dbuf
    __shared__ unsigned short Vts[2][64 * 64];   // [dh][key], swizzled, dbuf
    __shared__ unsigned short Ps[4][16 * 72];    // wave-private [query][key]

    const int tid = threadIdx.x, lane = tid & 63, w = tid >> 6;
    const int quad = lane >> 4, l16 = lane & 15;
    const int lr8 = lane >> 3, pg8 = lane & 7;
    // XCD swizzle (8 XCDs, assume round-robin bid%8): same bh -> same XCD
    const int bid = blockIdx.x;
    const int bh   = (bid & 7) * 4 + ((bid >> 3) & 3);   // 0..31
    const int pair = bid >> 5;                           // 0..15
    const int b = bh >> 4, h = bh & 15;

    const unsigned short* qb  = qkv + (size_t)(b * N_) * QKV_N + h * DH_;
    const unsigned short* kb  = qb + 1024;
    const unsigned short* vtb = vt + ((size_t)(b * 32) * 1024 + h * 64) * 64;

    bf16x8_t ones;
    #pragma unroll
    for (int j = 0; j < 8; j++) ones[j] = (short)0x3F80;   // bf16 1.0

    for (int phase = 0; phase < 2; phase++) {
        const int qt = phase ? (31 - pair) : pair;   // 64-query tile index
        const int qs = qt * 64;
        const int niter = qt + 1;

        __syncthreads();   // previous phase fully done with Qs/Ks/Vts

        // stage Q (2 instrs/wave) + K/V tile 0 into buffer 0
        #pragma unroll
        for (int i = 0; i < 2; i++) {
            const int rb = w * 16 + i * 8;
            const int r  = rb + lr8;
            const int g  = pg8 ^ (r & 7);
            async16(&qb[(size_t)(qs + r) * QKV_N + g * 8], &Qs[rb * 64]);
            async16(&kb[(size_t)r * QKV_N + g * 8], &Ks[0][rb * 64]);
            async16(&vtb[(size_t)r * 64 + g * 8],   &Vts[0][rb * 64]);
        }

        f32x4_t o[4] = {};
        f32x4_t lacc = {};
        bf16x8_t qf[2];

        for (int jt = 0; jt < niter; jt++) {
            // ends compute jt-1 (all waves) AND drains stage for buf[jt&1]
            __syncthreads();

            // prefetch next K/V tile into the other buffer
            if (jt + 1 < niter) {
                const int js = (jt + 1) * 64;
                const int bsel = (jt + 1) & 1;
                #pragma unroll
                for (int i = 0; i < 2; i++) {
                    const int rb = w * 16 + i * 8;
                    const int r  = rb + lr8;
                    const int g  = pg8 ^ (r & 7);
                    async16(&kb[(size_t)(js + r) * QKV_N + g * 8], &Ks[bsel][rb * 64]);
                    async16(&vtb[((size_t)(jt + 1) * 1024 + r) * 64 + g * 8],
                            &Vts[bsel][rb * 64]);
                }
            }
            const int buf = jt & 1;
            const int js = jt * 64;

            if (jt == 0) {
                #pragma unroll
                for (int k2 = 0; k2 < 2; k2++) {
                    const int g0 = k2 * 4 + quad;
                    qf[k2] = *(const bf16x8_t*)&Qs[
                        (w * 16 + l16) * 64 + (g0 ^ (l16 & 7)) * 8];
                }
            }

            // S^T = K . Q^T : m = 64 keys (4 kt), n = 16 queries of this wave
            f32x4_t s[4] = {};
            #pragma unroll
            for (int k2 = 0; k2 < 2; k2++) {
                const int g0 = k2 * 4 + quad;
                #pragma unroll
                for (int kt = 0; kt < 4; kt++) {
                    const bf16x8_t a = *(const bf16x8_t*)&Ks[buf][
                        (kt * 16 + l16) * 64 + (g0 ^ (l16 & 7)) * 8];
                    s[kt] = __builtin_amdgcn_mfma_f32_16x16x32_bf16(
                        a, qf[k2], s[kt], 0, 0, 0);
                }
            }

            // p = exp2(s) (Q pre-scaled); mask only on the diagonal tile
            const bool edge = (jt == niter - 1);
            #pragma unroll
            for (int kt = 0; kt < 4; kt++) {
                float p[4];
                #pragma unroll
                for (int r = 0; r < 4; r++) {
                    float sv = s[kt][r];
                    if (edge) {
                        const int key = js + kt * 16 + quad * 4 + r;
                        const int qy  = qs + w * 16 + l16;
                        if (key > qy) sv = -3e38f;
                    }
                    p[r] = exp2f(sv);
                }
                uint2 pk = { pk2bf(p[0], p[1]), pk2bf(p[2], p[3]) };
                *(uint2*)&Ps[w][l16 * 72 + kt * 16 + quad * 4] = pk;
            }
            // no barrier: Ps wave-private, lgkmcnt ordering suffices

            // O += P.V ; l += P.1
            #pragma unroll
            for (int k2 = 0; k2 < 2; k2++) {
                const int g0 = k2 * 4 + quad;
                const bf16x8_t ap = *(const bf16x8_t*)&Ps[w][
                    l16 * 72 + k2 * 32 + quad * 8];
                #pragma unroll
                for (int nt = 0; nt < 4; nt++) {
                    const bf16x8_t bv = *(const bf16x8_t*)&Vts[buf][
                        (nt * 16 + l16) * 64 + (g0 ^ (l16 & 7)) * 8];
                    o[nt] = __builtin_amdgcn_mfma_f32_16x16x32_bf16(
                        ap, bv, o[nt], 0, 0, 0);
                }
                lacc = __builtin_amdgcn_mfma_f32_16x16x32_bf16(
                    ap, ones, lacc, 0, 0, 0);
            }
        }

        // epilogue: C rows = queries (quad*4+r), cols = dh (nt*16+l16)
        #pragma unroll
        for (int r = 0; r < 4; r++) {
            const float inv = 1.0f / lacc[r];
            const int query = qs + w * 16 + quad * 4 + r;
            const int row = b * N_ + query;
            #pragma unroll
            for (int nt = 0; nt < 4; nt++) {
                const int col = h * DH_ + nt * 16 + l16;
                out[(size_t)row * (H_ * DH_) + col] = f2bf(o[nt][r] * inv);
            }
        }
    }
}

// ---------------------------------------------------------------------------
// Host launcher
// ---------------------------------------------------------------------------
extern "C" void kernel_launch(void* const* d_in, const int* in_sizes, int n_in,
                              void* d_out, int out_size, void* d_ws, size_t ws_size,
                              hipStream_t stream) {
    const float* x     = (const float*)d_in[0];
    const float* ln_g  = (const float*)d_in[1];
    const float* ln_b  = (const float*)d_in[2];
    const float* lnc_g = (const float*)d_in[3];
    const float* lnc_b = (const float*)d_in[4];
    const float* Wq    = (const float*)d_in[5];
    const float* Wkv   = (const float*)d_in[6];
    const float* Wo    = (const float*)d_in[7];

    char* ws = (char*)d_ws;
    const size_t MB = 1024 * 1024;
    unsigned short* qkv   = (unsigned short*)(ws + 0 * MB);    // [4096][3072] 24 MB (V region unused)
    unsigned short* vtbuf = (unsigned short*)(ws + 24 * MB);   // tiled V^T      8 MB
    unsigned short* xn    = (unsigned short*)(ws + 32 * MB);   // [4096][1024]  8 MB
    unsigned short* cn    = (unsigned short*)(ws + 40 * MB);   // [4096][1024]  8 MB
    unsigned short* wqkvT = (unsigned short*)(ws + 48 * MB);   // [3072][1024]  6 MB
    unsigned short* woT   = (unsigned short*)(ws + 54 * MB);   // [1024][1024]  2 MB
    unsigned short* ao    = xn;   // reuse: xn dead after QKV GEMM

    // LN (blocks 0..4095) + weight transposes (blocks 4096..8191), one dispatch
    ln_wt_kernel<<<8192, 256, 0, stream>>>(
        x, ln_g, ln_b, lnc_g, lnc_b, Wq, Wkv, Wo, xn, cn, wqkvT, woT);

    // fused Q+KV GEMM; Q pre-scaled; V written tiled-transposed to vtbuf
    gemm_kernel<128, true, true>
        <<<dim3(QKV_N / 128, BN_ROWS / 128), 256, 0, stream>>>(
        xn, cn, wqkvT, qkv, vtbuf, BN_ROWS, QKV_N, D_);

    flash_attn_kernel<<<B_ * H_ * 16, 256, 0, stream>>>(qkv, vtbuf, ao);

    // out = ao @ woT^T (fp32 out); BM=64 -> 512 blocks = 2/CU
    gemm_kernel<64, false, false>
        <<<dim3(D_ / 128, BN_ROWS / 64), 256, 0, stream>>>(
        ao, nullptr, woT, (float*)d_out, nullptr, BN_ROWS, D_, H_ * DH_);
}